// Round 2
// baseline (528.723 us; speedup 1.0000x reference)
//
#include <hip/hip_runtime.h>

typedef __attribute__((ext_vector_type(8))) short bf16x8;
typedef __attribute__((ext_vector_type(4))) float f32x4;

#define UR _Pragma("unroll")

__device__ __forceinline__ float bf2f(unsigned short u) {
    union { unsigned int i; float f; } v; v.i = ((unsigned int)u) << 16; return v.f;
}
__device__ __forceinline__ unsigned short f2bf(float f) {
    union { float f; unsigned int i; } v; v.f = f;
    unsigned int u = v.i;
    return (unsigned short)((u + 0x7FFFu + ((u >> 16) & 1u)) >> 16);
}
__device__ __forceinline__ uint2 pack4(f32x4 x) {
    uint2 o;
    o.x = (unsigned int)f2bf(x[0]) | ((unsigned int)f2bf(x[1]) << 16);
    o.y = (unsigned int)f2bf(x[2]) | ((unsigned int)f2bf(x[3]) << 16);
    return o;
}
// XOR-swizzled byte address into a [rows][256 bf16] LDS tile (512 B rows)
__device__ __forceinline__ int swz(int r, int c) {
    return r * 512 + (c ^ ((r & 7) << 4));
}

// ---------------- weight prep: fp32 [l][k][n] -> bf16 [branch][l][n][k] ----------------
__global__ __launch_bounds__(256)
void prep_kernel(const float* __restrict__ lw1, const float* __restrict__ rw1,
                 const float* __restrict__ lw2, const float* __restrict__ rw2,
                 unsigned short* __restrict__ w1t, unsigned short* __restrict__ w2t)
{
    int t = blockIdx.x * 256 + threadIdx.x;      // < 4*196608
    int tensor = t / 196608;
    int e = t - tensor * 196608;
    int l = e >> 16, rem = e & 65535;
    int n = rem >> 8, k = rem & 255;
    const float* src = (tensor == 0) ? lw1 : (tensor == 1) ? rw1 : (tensor == 2) ? lw2 : rw2;
    unsigned short* dst = ((tensor < 2) ? w1t : w2t) + (tensor & 1) * 196608;
    dst[e] = f2bf(src[(l << 16) + (k << 8) + n]);
}

// ---------------- conv: both branches, 17 taps, fp32 in -> bf16 ws ----------------
__global__ __launch_bounds__(256)
void conv_kernel(const float* __restrict__ inp,
                 const float* __restrict__ lpad, const float* __restrict__ rpad,
                 const float* __restrict__ lwt, const float* __restrict__ rwt,
                 uint2* __restrict__ wsL, uint2* __restrict__ wsR)
{
    int idx = blockIdx.x * 256 + threadIdx.x;    // < 32768*64
    int r = idx >> 6, d4 = idx & 63;
    int s = r & 2047;
    int c = d4 * 4;
    f32x4 aL = {0.f, 0.f, 0.f, 0.f}, aR = {0.f, 0.f, 0.f, 0.f};
    UR for (int j = -8; j <= 8; ++j) {
        int i = s + j;
        const float* src;
        if (i < 0)          src = lpad + (i + 8) * 256 + c;
        else if (i >= 2048) src = rpad + (i - 2048) * 256 + c;
        else                src = inp + (size_t)(r + j) * 256 + c;
        f32x4 v = *(const f32x4*)src;
        if (j <= 0) { float w = lwt[j + 8]; aL += v * w; }
        if (j >= 0) { float w = rwt[j];     aR += v * w; }
    }
    wsL[idx] = pack4(aL);
    wsR[idx] = pack4(aR);
}

// ---------------- fused 3-layer FFN stack, one branch-tile per block ----------------
__global__ __launch_bounds__(512, 2)
void mega_kernel(const unsigned short* __restrict__ convbf,   // [2][32768][256] bf16
                 const unsigned short* __restrict__ w1t,      // [2][3][256][256] bf16 (n-major)
                 const unsigned short* __restrict__ w2t,
                 const float* __restrict__ b1L, const float* __restrict__ b1R,
                 const float* __restrict__ b2L, const float* __restrict__ b2R,
                 const float* __restrict__ gL,  const float* __restrict__ gR,
                 const float* __restrict__ bbL, const float* __restrict__ bbR,
                 float* __restrict__ out)
{
    __shared__ unsigned short YH[128 * 256];     // 64 KB, holds Y then H alternately
    __shared__ float red[4][128][2];             // 4 KB, LN cross-wave partials

    const int tid = threadIdx.x;
    const int wv = tid >> 6;
    const int ln = tid & 63;
    const int lr = ln & 15;
    const int lh = ln >> 4;
    const int wm = wv >> 1;      // d-tile 0..3
    const int wn = wv & 1;       // r-tile 0..1

    const int bid  = blockIdx.x;
    const int br   = bid >> 8;       // branch 0=left 1=right
    const int tile = bid & 255;
    const int r0   = tile * 128;

    const unsigned short* cv  = convbf + (size_t)br * (32768u * 256u);
    const unsigned short* W1b = w1t + (size_t)br * 196608;
    const unsigned short* W2b = w2t + (size_t)br * 196608;
    const float* B1 = br ? b1R : b1L;
    const float* B2 = br ? b2R : b2L;
    const float* G  = br ? gR  : gL;
    const float* Bb = br ? bbR : bbL;

    int rr[4], dd[4], hh[4];
    UR for (int n = 0; n < 4; ++n) rr[n] = wn * 64 + n * 16 + lr;       // sample row (C col)
    UR for (int m = 0; m < 4; ++m) dd[m] = wm * 64 + m * 16 + lh * 4;   // feature dim (C row base)
    UR for (int m = 0; m < 4; ++m) hh[m] = wm * 64 + m * 16 + lr;       // A-frag row

    // load residual x^T fragments (fp32) from bf16 conv output
    f32x4 x[4][4];
    UR for (int m = 0; m < 4; ++m)
      UR for (int n = 0; n < 4; ++n) {
        uint2 raw = *(const uint2*)(cv + (size_t)(r0 + rr[n]) * 256 + dd[m]);
        f32x4 v;
        v[0] = bf2f((unsigned short)(raw.x & 0xffffu));
        v[1] = bf2f((unsigned short)(raw.x >> 16));
        v[2] = bf2f((unsigned short)(raw.y & 0xffffu));
        v[3] = bf2f((unsigned short)(raw.y >> 16));
        x[m][n] = v;
      }

    for (int lay = 0; lay < 3; ++lay) {
        // ------- LayerNorm: stats from fp32 frags -------
        UR for (int n = 0; n < 4; ++n) {
            float s = 0.f, q = 0.f;
            UR for (int m = 0; m < 4; ++m)
              UR for (int r = 0; r < 4; ++r) { float v = x[m][n][r]; s += v; q += v * v; }
            s += __shfl_xor(s, 16); q += __shfl_xor(q, 16);
            s += __shfl_xor(s, 32); q += __shfl_xor(q, 32);
            if (lh == 0) {
                red[wm][wn * 64 + n * 16 + lr][0] = s;
                red[wm][wn * 64 + n * 16 + lr][1] = q;
            }
        }
        __syncthreads();    // red ready; also guards prev-layer H reads before Y overwrite
        float mean[4], rstd[4];
        UR for (int n = 0; n < 4; ++n) {
            int row = wn * 64 + n * 16 + lr;
            float S = 0.f, Q = 0.f;
            UR for (int w = 0; w < 4; ++w) { S += red[w][row][0]; Q += red[w][row][1]; }
            float mu = S * (1.f / 256.f);
            float var = Q * (1.f / 256.f) - mu * mu;
            mean[n] = mu;
            rstd[n] = rsqrtf(var + 1e-6f);
        }
        f32x4 gf[4], bfr_[4];
        UR for (int m = 0; m < 4; ++m) {
            gf[m]   = *(const f32x4*)(G  + lay * 256 + dd[m]);
            bfr_[m] = *(const f32x4*)(Bb + lay * 256 + dd[m]);
        }
        UR for (int m = 0; m < 4; ++m)
          UR for (int n = 0; n < 4; ++n) {
            f32x4 y;
            UR for (int r = 0; r < 4; ++r)
                y[r] = (x[m][n][r] - mean[n]) * rstd[n] * gf[m][r] + bfr_[m][r];
            *(uint2*)((char*)YH + swz(rr[n], dd[m] * 2)) = pack4(y);
          }
        __syncthreads();    // Y ready

        // ------- GEMM1: C1^T[h][r] = W1T · Y^T -------
        const unsigned short* Wl = W1b + lay * 65536;
        f32x4 acc[4][4];
        UR for (int m = 0; m < 4; ++m)
          UR for (int n = 0; n < 4; ++n) acc[m][n] = (f32x4){0.f, 0.f, 0.f, 0.f};
        UR for (int kk = 0; kk < 8; ++kk) {
            bf16x8 a[4], b[4];
            UR for (int m = 0; m < 4; ++m)
                a[m] = *(const bf16x8*)(Wl + hh[m] * 256 + kk * 32 + lh * 8);
            UR for (int n = 0; n < 4; ++n)
                b[n] = *(const bf16x8*)((const char*)YH + swz(rr[n], kk * 64 + lh * 16));
            UR for (int m = 0; m < 4; ++m)
              UR for (int n = 0; n < 4; ++n)
                acc[m][n] = __builtin_amdgcn_mfma_f32_16x16x32_bf16(a[m], b[n], acc[m][n], 0, 0, 0);
        }
        f32x4 b1f[4];
        UR for (int m = 0; m < 4; ++m) b1f[m] = *(const f32x4*)(B1 + lay * 256 + dd[m]);
        __syncthreads();    // all waves done reading Y
        UR for (int m = 0; m < 4; ++m)
          UR for (int n = 0; n < 4; ++n) {
            f32x4 h;
            UR for (int r = 0; r < 4; ++r) h[r] = fmaxf(acc[m][n][r] + b1f[m][r], 0.f);
            *(uint2*)((char*)YH + swz(rr[n], dd[m] * 2)) = pack4(h);
          }
        __syncthreads();    // H ready

        // ------- GEMM2: C2^T[d][r] = W2T · H^T -------
        const unsigned short* W2l = W2b + lay * 65536;
        UR for (int m = 0; m < 4; ++m)
          UR for (int n = 0; n < 4; ++n) acc[m][n] = (f32x4){0.f, 0.f, 0.f, 0.f};
        UR for (int kk = 0; kk < 8; ++kk) {
            bf16x8 a[4], b[4];
            UR for (int m = 0; m < 4; ++m)
                a[m] = *(const bf16x8*)(W2l + hh[m] * 256 + kk * 32 + lh * 8);
            UR for (int n = 0; n < 4; ++n)
                b[n] = *(const bf16x8*)((const char*)YH + swz(rr[n], kk * 64 + lh * 16));
            UR for (int m = 0; m < 4; ++m)
              UR for (int n = 0; n < 4; ++n)
                acc[m][n] = __builtin_amdgcn_mfma_f32_16x16x32_bf16(a[m], b[n], acc[m][n], 0, 0, 0);
        }
        f32x4 b2f[4];
        UR for (int m = 0; m < 4; ++m) b2f[m] = *(const f32x4*)(B2 + lay * 256 + dd[m]);
        UR for (int m = 0; m < 4; ++m)
          UR for (int n = 0; n < 4; ++n)
            UR for (int r = 0; r < 4; ++r)
                x[m][n][r] += acc[m][n][r] + b2f[m][r];

        // ------- store layer output (and duplicate final) -------
        float* outL = out + ((size_t)lay * 32768 + r0) * 512 + br * 256;
        UR for (int m = 0; m < 4; ++m)
          UR for (int n = 0; n < 4; ++n) {
            float* p = outL + (size_t)rr[n] * 512 + dd[m];
            *(f32x4*)p = x[m][n];
            if (lay == 2) *(f32x4*)(p + 16777216) = x[m][n];
          }
    }
}

extern "C" void kernel_launch(void* const* d_in, const int* in_sizes, int n_in,
                              void* d_out, int out_size, void* d_ws, size_t ws_size,
                              hipStream_t stream)
{
    const float* inputs = (const float*)d_in[0];
    const float* lpad = (const float*)d_in[1];
    const float* rpad = (const float*)d_in[2];
    const float* lwt  = (const float*)d_in[3];
    const float* rwt  = (const float*)d_in[4];
    const float* lw1  = (const float*)d_in[5];
    const float* lb1  = (const float*)d_in[6];
    const float* lw2  = (const float*)d_in[7];
    const float* lb2  = (const float*)d_in[8];
    const float* lg   = (const float*)d_in[9];
    const float* lbb  = (const float*)d_in[10];
    const float* rw1  = (const float*)d_in[11];
    const float* rb1  = (const float*)d_in[12];
    const float* rw2  = (const float*)d_in[13];
    const float* rb2  = (const float*)d_in[14];
    const float* rg   = (const float*)d_in[15];
    const float* rbb  = (const float*)d_in[16];

    char* ws = (char*)d_ws;
    // ws map (bytes): [0, 16M) convL bf16 | [16M, 32M) convR bf16 | w1t | w2t  (~35.1 MB total)
    unsigned short* convb = (unsigned short*)ws;
    unsigned short* w1t   = (unsigned short*)(ws + 33554432);
    unsigned short* w2t   = (unsigned short*)(ws + 33554432 + 786432);

    prep_kernel<<<3072, 256, 0, stream>>>(lw1, rw1, lw2, rw2, w1t, w2t);
    conv_kernel<<<8192, 256, 0, stream>>>(inputs, lpad, rpad, lwt, rwt,
                                          (uint2*)convb, (uint2*)(convb + 32768u * 256u));
    mega_kernel<<<512, 512, 0, stream>>>(convb, w1t, w2t,
                                         lb1, rb1, lb2, rb2, lg, rg, lbb, rbb,
                                         (float*)d_out);
}